// Round 1
// baseline (205.400 us; speedup 1.0000x reference)
//
#include <hip/hip_runtime.h>
#include <hip/hip_bf16.h>

// Problem constants (from reference)
#define N_ELEM   5
#define N_ROWS   16
#define NW       512            // N (image width/height, samples per row)
#define MB_ROWS  8192           // N_ROWS * NW
#define N_LINES  12
#define SCALE    (0.01f / 512.0f)   // SAMPLE_SIZE_CM / N
#define FL_CONST 170.0f             // PROBE_CTS * FL_RATIO * SA_ADJ * SA_THETA

__global__ __launch_bounds__(512, 2) void fused_fl_kernel(
    const float* __restrict__ xp,       // (5, 16, 512, 512)
    const float* __restrict__ attCS,    // (5,)
    const float* __restrict__ dfl,      // (12,)
    const float* __restrict__ theta_p,  // (1,)
    const int*   __restrict__ lidx,     // (12,)
    float*       __restrict__ out)      // fl_sig (12*8192) ++ transmission (8192)
{
    const int b    = blockIdx.x;        // row index 0..8191
    const int s    = threadIdx.x;       // sample 0..511
    const int c    = b >> 9;            // channel 0..15
    const int irow = b & 511;           // image row 0..511
    const int lane = threadIdx.x & 63;
    const int wave = threadIdx.x >> 6;  // 0..7

    // ---- rotation source coords (depend only on irow, s) ----
    const float theta = theta_p[0];
    const float cs = cosf(theta);
    const float sn = sinf(theta);
    const float Wf = 512.0f;

    const float gx = (2.0f * (float)s    + 1.0f) / Wf - 1.0f;
    const float gy = (2.0f * (float)irow + 1.0f) / Wf - 1.0f;
    const float x_in = cs * gx - sn * gy;
    const float y_in = sn * gx + cs * gy;
    float ix = ((x_in + 1.0f) * Wf - 1.0f) * 0.5f;
    float iy = ((y_in + 1.0f) * Wf - 1.0f) * 0.5f;
    ix = fminf(fmaxf(ix, 0.0f), 511.0f);
    iy = fminf(fmaxf(iy, 0.0f), 511.0f);

    const float x0f = floorf(ix);
    const float y0f = floorf(iy);
    const float wx = ix - x0f;
    const float wy = iy - y0f;
    const int x0 = (int)x0f;
    const int y0 = (int)y0f;
    const int x1 = min(x0 + 1, 511);
    const int y1 = min(y0 + 1, 511);

    const float w00 = (1.0f - wx) * (1.0f - wy);
    const float w01 = wx * (1.0f - wy);
    const float w10 = (1.0f - wx) * wy;
    const float w11 = wx * wy;

    const size_t o00 = (size_t)y0 * 512 + x0;
    const size_t o01 = (size_t)y0 * 512 + x1;
    const size_t o10 = (size_t)y1 * 512 + x0;
    const size_t o11 = (size_t)y1 * 512 + x1;

    // ---- gather conc[e] and lac ----
    const size_t plane_c = (size_t)c * (512 * 512);
    const size_t estride = (size_t)N_ROWS * 512 * 512;  // 16*512*512

    float conc[N_ELEM];
    float lac = 0.0f;
#pragma unroll
    for (int e = 0; e < N_ELEM; ++e) {
        const float* p = xp + (size_t)e * estride + plane_c;
        conc[e] = w00 * p[o00] + w01 * p[o01] + w10 * p[o10] + w11 * p[o11];
        lac = fmaf(attCS[e], conc[e], lac);
    }

    // ---- block-wide scan of lac along s (512 elems, 8 waves) ----
    float v = lac;
#pragma unroll
    for (int off = 1; off < 64; off <<= 1) {
        float n = __shfl_up(v, off, 64);
        if (lane >= off) v += n;
    }
    // v = wave-inclusive scan

    __shared__ float wsum[8];
    if (lane == 63) wsum[wave] = v;
    __syncthreads();

    float woff = 0.0f, tot = 0.0f;
#pragma unroll
    for (int w = 0; w < 8; ++w) {
        float ws = wsum[w];
        if (w < wave) woff += ws;
        tot += ws;
    }
    const float incl = v + woff;        // inclusive prefix of lac
    const float excl = incl - lac;      // exclusive prefix

    const float att = __expf(-excl * SCALE);

    // transmission[b] = total * SCALE (not exponentiated)
    if (threadIdx.x == 0) {
        out[(size_t)N_LINES * MB_ROWS + b] = tot * SCALE;
    }

    // ---- 5 block reductions: S[e] = sum_s att * conc[e] ----
    float se[N_ELEM];
#pragma unroll
    for (int e = 0; e < N_ELEM; ++e) se[e] = att * conc[e];

#pragma unroll
    for (int off = 32; off > 0; off >>= 1) {
#pragma unroll
        for (int e = 0; e < N_ELEM; ++e) se[e] += __shfl_down(se[e], off, 64);
    }

    __shared__ float red[8][N_ELEM];
    if (lane == 0) {
#pragma unroll
        for (int e = 0; e < N_ELEM; ++e) red[wave][e] = se[e];
    }
    __syncthreads();

    __shared__ float sE[N_ELEM];
    if (threadIdx.x < N_ELEM) {
        float t = 0.0f;
#pragma unroll
        for (int w = 0; w < 8; ++w) t += red[w][threadIdx.x];
        sE[threadIdx.x] = t;
    }
    __syncthreads();

    if (threadIdx.x < N_LINES) {
        const int l = threadIdx.x;
        out[(size_t)l * MB_ROWS + b] = FL_CONST * dfl[l] * sE[lidx[l]];
    }
}

extern "C" void kernel_launch(void* const* d_in, const int* in_sizes, int n_in,
                              void* d_out, int out_size, void* d_ws, size_t ws_size,
                              hipStream_t stream) {
    const float* xp     = (const float*)d_in[0];
    const float* attCS  = (const float*)d_in[1];
    const float* dfl    = (const float*)d_in[2];
    const float* theta  = (const float*)d_in[3];
    const int*   lidx   = (const int*)d_in[4];
    float* out = (float*)d_out;

    fused_fl_kernel<<<MB_ROWS, 512, 0, stream>>>(xp, attCS, dfl, theta, lidx, out);
}

// Round 4
// 182.324 us; speedup vs baseline: 1.1266x; 1.1266x over previous
//
#include <hip/hip_runtime.h>
#include <hip/hip_bf16.h>

// Problem constants
#define N_ELEM   5
#define NW       512
#define MB_ROWS  8192            // 16 * 512
#define N_LINES  12
#define SCALE    (0.01f / 512.0f)
#define FL_CONST 170.0f          // PROBE_CTS * FL_RATIO * SA_ADJ * SA_THETA

// Block = 8 output rows (one channel c) x full 512 samples, processed in 8
// chunks of 64 samples. Thread (r = tid&7, sc = tid>>3) handles samples
// s = sc + 64k of row irow0+r. Each wave therefore covers an 8x8 output
// patch -> ~11x11 px source footprint -> ~3x fewer cache-line transactions
// per gather instruction than the 1-row-per-block layout.
__global__ __launch_bounds__(512) void fused_fl_kernel(
    const float* __restrict__ xp,       // (5, 16, 512, 512)
    const float* __restrict__ attCS,    // (5,)
    const float* __restrict__ dfl,      // (12,)
    const float* __restrict__ theta_p,  // (1,)
    const int*   __restrict__ lidx,     // (12,)
    float*       __restrict__ out)      // fl_sig (12*8192) ++ transmission (8192)
{
    // ---- block decode: 1024 blocks -> (c, row-group g). bid&7 ties channel
    // to XCD (round-robin dispatch) for L2 affinity.
    const int bid = blockIdx.x;
    const int t   = bid >> 3;                 // 0..127
    const int c   = (bid & 7) + 8 * (t >> 6); // 0..15
    const int g   = t & 63;                   // 0..63
    const int irow0 = g << 3;

    const int tid  = threadIdx.x;
    const int r    = tid & 7;    // row within group
    const int sc   = tid >> 3;   // 0..63 column slot
    const int lane = tid & 63;
    const int w    = tid >> 6;   // wave id 0..7; wave w scans row r==w

    const float theta = theta_p[0];
    const float cs = cosf(theta);
    const float sn = sinf(theta);

    const int irow = irow0 + r;
    const float gy = (2.0f * (float)irow + 1.0f) * (1.0f / 512.0f) - 1.0f;

    const size_t plane_c = (size_t)c * (512 * 512);
    const size_t estride = (size_t)16 * 512 * 512;
    const float* base = xp + plane_c;

    const float a0 = attCS[0], a1 = attCS[1], a2 = attCS[2], a3 = attCS[3], a4 = attCS[4];

    // LDS: stride 72 on the 64-slot dim => 2-way bank aliasing only (free)
    __shared__ float s_lac[2][8][72];
    __shared__ float s_att[2][8][72];
    __shared__ float s_part[8][8][5];   // [wave][row][elem]
    __shared__ float s_S[8][5];         // [row][elem]

    float se0 = 0.f, se1 = 0.f, se2 = 0.f, se3 = 0.f, se4 = 0.f;
    float carry = 0.f;                  // running row-sum for wave w's row

    for (int k = 0; k < 8; ++k) {
        const int kb = k & 1;
        const int s = sc + (k << 6);

        // ---- rotation coords ----
        const float gx = (2.0f * (float)s + 1.0f) * (1.0f / 512.0f) - 1.0f;
        const float x_in = cs * gx - sn * gy;
        const float y_in = sn * gx + cs * gy;
        float ix = ((x_in + 1.0f) * 512.0f - 1.0f) * 0.5f;
        float iy = ((y_in + 1.0f) * 512.0f - 1.0f) * 0.5f;
        ix = fminf(fmaxf(ix, 0.0f), 511.0f);
        iy = fminf(fmaxf(iy, 0.0f), 511.0f);

        const float x0f = floorf(ix);
        const float y0f = floorf(iy);
        const float wx = ix - x0f;
        const float wy = iy - y0f;
        const int x0 = (int)x0f;
        const int y0 = (int)y0f;
        const int x1 = min(x0 + 1, 511);
        const int y1 = min(y0 + 1, 511);

        const float w00 = (1.0f - wx) * (1.0f - wy);
        const float w01 = wx * (1.0f - wy);
        const float w10 = (1.0f - wx) * wy;
        const float w11 = wx * wy;

        const int o00 = y0 * 512 + x0;
        const int o01 = y0 * 512 + x1;
        const int o10 = y1 * 512 + x0;
        const int o11 = y1 * 512 + x1;

        // ---- gather 5 elements ----
        float c0, c1, c2, c3, c4;
        {
            const float* p = base;
            c0 = w00 * p[o00] + w01 * p[o01] + w10 * p[o10] + w11 * p[o11];
            p += estride;
            c1 = w00 * p[o00] + w01 * p[o01] + w10 * p[o10] + w11 * p[o11];
            p += estride;
            c2 = w00 * p[o00] + w01 * p[o01] + w10 * p[o10] + w11 * p[o11];
            p += estride;
            c3 = w00 * p[o00] + w01 * p[o01] + w10 * p[o10] + w11 * p[o11];
            p += estride;
            c4 = w00 * p[o00] + w01 * p[o01] + w10 * p[o10] + w11 * p[o11];
        }
        float lac = a0 * c0;
        lac = fmaf(a1, c1, lac);
        lac = fmaf(a2, c2, lac);
        lac = fmaf(a3, c3, lac);
        lac = fmaf(a4, c4, lac);

        s_lac[kb][r][sc] = lac;
        __syncthreads();

        // ---- per-wave scan: wave w scans row w's 64 values ----
        const float lv = s_lac[kb][w][lane];
        float v = lv;
#pragma unroll
        for (int off = 1; off < 64; off <<= 1) {
            float n = __shfl_up(v, off, 64);
            if (lane >= off) v += n;
        }
        const float tot = __shfl(v, 63, 64);
        const float excl = carry + v - lv;       // exclusive prefix incl. carry
        s_att[kb][w][lane] = __expf(-excl * SCALE);
        carry += tot;
        __syncthreads();

        // ---- accumulate fluorescence partials in registers ----
        const float att = s_att[kb][r][sc];
        se0 = fmaf(att, c0, se0);
        se1 = fmaf(att, c1, se1);
        se2 = fmaf(att, c2, se2);
        se3 = fmaf(att, c3, se3);
        se4 = fmaf(att, c4, se4);
    }

    // ---- transmission: carry now holds full row sum for wave w's row ----
    if (lane == 0) {
        out[(size_t)N_LINES * MB_ROWS + (size_t)c * 512 + irow0 + w] = carry * SCALE;
    }

    // ---- reduce se over sc. Within a wave, lanes sharing (lane&7)==r ----
#pragma unroll
    for (int off = 32; off >= 8; off >>= 1) {
        se0 += __shfl_down(se0, off, 64);
        se1 += __shfl_down(se1, off, 64);
        se2 += __shfl_down(se2, off, 64);
        se3 += __shfl_down(se3, off, 64);
        se4 += __shfl_down(se4, off, 64);
    }
    if (lane < 8) {   // lane == r holds partial for row=lane over this wave's sc
        s_part[w][lane][0] = se0;
        s_part[w][lane][1] = se1;
        s_part[w][lane][2] = se2;
        s_part[w][lane][3] = se3;
        s_part[w][lane][4] = se4;
    }
    __syncthreads();

    if (tid < 40) {   // (row rr, elem e): sum across 8 waves
        const int rr = tid & 7;
        const int e  = tid >> 3;
        float S = 0.f;
#pragma unroll
        for (int ww = 0; ww < 8; ++ww) S += s_part[ww][rr][e];
        s_S[rr][e] = S;
    }
    __syncthreads();

    if (tid < 96) {   // (row rr, line l)
        const int rr = tid / 12;
        const int l  = tid % 12;
        const size_t b = (size_t)c * 512 + irow0 + rr;
        out[(size_t)l * MB_ROWS + b] = FL_CONST * dfl[l] * s_S[rr][lidx[l]];
    }
}

extern "C" void kernel_launch(void* const* d_in, const int* in_sizes, int n_in,
                              void* d_out, int out_size, void* d_ws, size_t ws_size,
                              hipStream_t stream) {
    const float* xp    = (const float*)d_in[0];
    const float* attCS = (const float*)d_in[1];
    const float* dfl   = (const float*)d_in[2];
    const float* theta = (const float*)d_in[3];
    const int*   lidx  = (const int*)d_in[4];
    float* out = (float*)d_out;

    fused_fl_kernel<<<MB_ROWS / 8, 512, 0, stream>>>(xp, attCS, dfl, theta, lidx, out);
}